// Round 1
// baseline (249.072 us; speedup 1.0000x reference)
//
#include <hip/hip_runtime.h>
#include <hip/hip_bf16.h>

#define BDIM 8
#define LDIM 128
#define TDIM 64
#define NFEAT 1024
#define HNUM 16
#define DH 64

// ---------------------------------------------------------------------------
// Kernel 1: km[b,l,f] = mean over t of kv[b,l,t,f].  One block per (b,l) row.
// ---------------------------------------------------------------------------
__global__ __launch_bounds__(256) void mean_kernel(const float* __restrict__ kv,
                                                   float* __restrict__ km) {
  const int bl = blockIdx.x;  // b*L + l
  const float* src = kv + (size_t)bl * (TDIM * NFEAT) + threadIdx.x * 4;
  float4 acc = make_float4(0.f, 0.f, 0.f, 0.f);
#pragma unroll 4
  for (int t = 0; t < TDIM; ++t) {
    const float4 v = *(const float4*)(src + t * NFEAT);
    acc.x += v.x; acc.y += v.y; acc.z += v.z; acc.w += v.w;
  }
  const float s = 1.f / TDIM;
  const float4 o = make_float4(acc.x * s, acc.y * s, acc.z * s, acc.w * s);
  *(float4*)(km + (size_t)bl * NFEAT + threadIdx.x * 4) = o;
}

// ---------------------------------------------------------------------------
// Kernel 2: fused q-proj, k-proj (folded), QK^T, softmax -> attn[b1,h,b2,l]
// One block per (b1,h), 128 threads (one per l).
// qk[b2,i] = sum_d qp[b2,d]*Wk[d,i]  lets us skip materializing kp:
// attw[b2,l] = km_l . qk[b2] (+ const shift from bk, dropped: softmax-invariant)
// ---------------------------------------------------------------------------
__global__ __launch_bounds__(128) void attn_kernel(const float* __restrict__ q,
                                                   const float* __restrict__ km,
                                                   const float* __restrict__ Wq,
                                                   const float* __restrict__ bq,
                                                   const float* __restrict__ Wk,
                                                   float* __restrict__ attn) {
  __shared__ float qp_s[BDIM * DH];   // 512
  __shared__ float qk_s[BDIM * DH];   // 512
  __shared__ float sw[BDIM * LDIM];   // 1024
  __shared__ float mred[BDIM], ired[BDIM];
  const int b1 = blockIdx.x;
  const int h  = blockIdx.y;
  const int tid = threadIdx.x;

  // phase 1: qp[b2][d] = bq[d] + sum_i q[b2][h*64+i]*Wq[d][i]   (4 entries/thread)
  {
    const int e0 = tid * 4;
    const int b2 = e0 >> 6;
    const int d0 = e0 & 63;
    float a0 = bq[d0], a1 = bq[d0 + 1], a2 = bq[d0 + 2], a3 = bq[d0 + 3];
    const float* qrow = q + b2 * NFEAT + h * DH;
#pragma unroll 4
    for (int i = 0; i < DH; ++i) {
      const float qv = qrow[i];
      a0 += qv * Wq[(d0 + 0) * DH + i];
      a1 += qv * Wq[(d0 + 1) * DH + i];
      a2 += qv * Wq[(d0 + 2) * DH + i];
      a3 += qv * Wq[(d0 + 3) * DH + i];
    }
    qp_s[e0 + 0] = a0; qp_s[e0 + 1] = a1; qp_s[e0 + 2] = a2; qp_s[e0 + 3] = a3;
  }
  __syncthreads();
  // phase 2: qk[b2][i] = sum_d qp[b2][d]*Wk[d][i]
  {
    const int e0 = tid * 4;
    const int b2 = e0 >> 6;
    const int i0 = e0 & 63;
    float a0 = 0, a1 = 0, a2 = 0, a3 = 0;
#pragma unroll 4
    for (int d = 0; d < DH; ++d) {
      const float qpv = qp_s[b2 * DH + d];
      const float4 wk4 = *(const float4*)(Wk + d * DH + i0);
      a0 += qpv * wk4.x; a1 += qpv * wk4.y; a2 += qpv * wk4.z; a3 += qpv * wk4.w;
    }
    qk_s[e0 + 0] = a0; qk_s[e0 + 1] = a1; qk_s[e0 + 2] = a2; qk_s[e0 + 3] = a3;
  }
  __syncthreads();
  // phase 3: per l: s[b2] = dot(km_row, qk[b2]) * 1/sqrt(64)
  const int l = tid;
  {
    const float* kmrow = km + (size_t)(b1 * LDIM + l) * NFEAT + h * DH;
    float s[8] = {0, 0, 0, 0, 0, 0, 0, 0};
#pragma unroll
    for (int i4 = 0; i4 < DH / 4; ++i4) {
      const float4 kmv = *(const float4*)(kmrow + i4 * 4);
#pragma unroll
      for (int b2 = 0; b2 < 8; ++b2) {
        const float4 qk4 = *(const float4*)(qk_s + b2 * DH + i4 * 4);
        s[b2] += kmv.x * qk4.x + kmv.y * qk4.y + kmv.z * qk4.z + kmv.w * qk4.w;
      }
    }
#pragma unroll
    for (int b2 = 0; b2 < 8; ++b2) sw[b2 * LDIM + l] = s[b2] * 0.125f;
  }
  __syncthreads();
  // phase 4: softmax over l for each b2
  if (tid < 8) {
    const int b2 = tid;
    float m = -1e30f;
    for (int j = 0; j < LDIM; ++j) m = fmaxf(m, sw[b2 * LDIM + j]);
    float ssum = 0.f;
    for (int j = 0; j < LDIM; ++j) ssum += expf(sw[b2 * LDIM + j] - m);
    mred[b2] = m;
    ired[b2] = 1.f / ssum;
  }
  __syncthreads();
  float* abase = attn + ((size_t)(b1 * HNUM + h) * BDIM) * LDIM + l;
#pragma unroll
  for (int b2 = 0; b2 < 8; ++b2) {
    abase[b2 * LDIM] = expf(sw[b2 * LDIM + l] - mred[b2]) * ired[b2];
  }
}

// ---------------------------------------------------------------------------
// Kernel 3: Weff[f, h*64+i] = sum_d Wo[f,h*64+d]*Wv[d,i]
//           beff[f] = bo[f] + sum_g bv[g%64]*Wo[f,g]
// One block per f (1024 blocks, 256 threads).
// ---------------------------------------------------------------------------
__global__ __launch_bounds__(256) void weff_kernel(const float* __restrict__ Wo,
                                                   const float* __restrict__ Wv,
                                                   const float* __restrict__ bv,
                                                   const float* __restrict__ bo,
                                                   float* __restrict__ Weff,
                                                   float* __restrict__ beff) {
  __shared__ float worow[NFEAT];
  __shared__ float red[256];
  const int f = blockIdx.x;
  const int tid = threadIdx.x;
  *(float4*)(worow + tid * 4) = *(const float4*)(Wo + (size_t)f * NFEAT + tid * 4);
  __syncthreads();
  const int g0 = tid * 4;
  const int hbase = (g0 >> 6) << 6;
  const int i0 = g0 & 63;
  float a0 = 0, a1 = 0, a2 = 0, a3 = 0;
#pragma unroll 4
  for (int d = 0; d < DH; ++d) {
    const float wod = worow[hbase + d];
    const float4 wv4 = *(const float4*)(Wv + d * DH + i0);
    a0 += wod * wv4.x; a1 += wod * wv4.y; a2 += wod * wv4.z; a3 += wod * wv4.w;
  }
  float4 o = make_float4(a0, a1, a2, a3);
  *(float4*)(Weff + (size_t)f * NFEAT + g0) = o;
  // beff partial: this thread's 4 g values
  red[tid] = worow[g0 + 0] * bv[i0 + 0] + worow[g0 + 1] * bv[i0 + 1] +
             worow[g0 + 2] * bv[i0 + 2] + worow[g0 + 3] * bv[i0 + 3];
  __syncthreads();
  for (int sft = 128; sft > 0; sft >>= 1) {
    if (tid < sft) red[tid] += red[tid + sft];
    __syncthreads();
  }
  if (tid == 0) beff[f] = bo[f] + red[0];
}

// ---------------------------------------------------------------------------
// Kernel 4: pooled[b1][t][b2][f] = sum_l attn[b1, f/64, b2, l] * kv[b1,l,t,f]
// Grid (b1, t, ftile of 256 f), 64 threads, each thread one float4 of f,
// 8 accumulators (one per b2).  Streams kv exactly once (256 MB).
// ---------------------------------------------------------------------------
__global__ __launch_bounds__(64) void pool_kernel(const float* __restrict__ kv,
                                                  const float* __restrict__ attn,
                                                  float* __restrict__ pooled) {
  __shared__ float wlds[4 * BDIM * LDIM];  // 4096 floats: attn for this b1, 4 heads
  const int b1 = blockIdx.x;
  const int t = blockIdx.y;
  const int ftile = blockIdx.z;
  const int tid = threadIdx.x;
  {
    // attn[b1, ftile*4 .. ftile*4+3, :, :] is contiguous (4096 floats)
    const float* src = attn + ((size_t)(b1 * HNUM + ftile * 4)) * (BDIM * LDIM);
#pragma unroll
    for (int j = 0; j < 16; ++j) {
      const int idx = (j * 64 + tid) * 4;
      *(float4*)(wlds + idx) = *(const float4*)(src + idx);
    }
  }
  __syncthreads();
  const int f = ftile * 256 + tid * 4;
  const int hh = tid >> 4;  // local head within the 4 loaded
  const float* kvbase = kv + ((size_t)b1 * LDIM) * (TDIM * NFEAT) + t * NFEAT + f;
  float4 acc[8];
#pragma unroll
  for (int b2 = 0; b2 < 8; ++b2) acc[b2] = make_float4(0.f, 0.f, 0.f, 0.f);
  const float* wbase = wlds + hh * (BDIM * LDIM);
#pragma unroll 2
  for (int l = 0; l < LDIM; ++l) {
    const float4 v = *(const float4*)(kvbase + (size_t)l * (TDIM * NFEAT));
#pragma unroll
    for (int b2 = 0; b2 < 8; ++b2) {
      const float w = wbase[b2 * LDIM + l];
      acc[b2].x += w * v.x; acc[b2].y += w * v.y;
      acc[b2].z += w * v.z; acc[b2].w += w * v.w;
    }
  }
  float* obase = pooled + ((size_t)(b1 * TDIM + t) * BDIM) * NFEAT + f;
#pragma unroll
  for (int b2 = 0; b2 < 8; ++b2) {
    *(float4*)(obase + b2 * NFEAT) = acc[b2];
  }
}

// ---------------------------------------------------------------------------
// Kernel 5: out[r][f] = sum_k A[r][k]*Weff[f][k] + beff[f]
// A = pooled [4096][1024] row-major (rows ordered (b1,t,b2) = output order).
// 64x64 output tile per block, BK=32, 256 threads, 4x4 micro-tile. fp32.
// ---------------------------------------------------------------------------
__global__ __launch_bounds__(256) void gemm_kernel(const float* __restrict__ A,
                                                   const float* __restrict__ W,
                                                   const float* __restrict__ beff,
                                                   float* __restrict__ out) {
  __shared__ float As[32][68];
  __shared__ float Ws[32][68];
  const int tid = threadIdx.x;
  const int nBase = blockIdx.x * 64;
  const int mBase = blockIdx.y * 64;
  const int tx = tid & 15;
  const int ty = tid >> 4;
  float acc[4][4] = {{0.f}};
  for (int k0 = 0; k0 < NFEAT; k0 += 32) {
#pragma unroll
    for (int rep = 0; rep < 2; ++rep) {
      const int lin = tid + rep * 256;
      const int m = lin >> 3;
      const int k4 = (lin & 7) * 4;
      const float4 av = *(const float4*)(A + (size_t)(mBase + m) * NFEAT + k0 + k4);
      As[k4 + 0][m] = av.x; As[k4 + 1][m] = av.y;
      As[k4 + 2][m] = av.z; As[k4 + 3][m] = av.w;
      const float4 wv = *(const float4*)(W + (size_t)(nBase + m) * NFEAT + k0 + k4);
      Ws[k4 + 0][m] = wv.x; Ws[k4 + 1][m] = wv.y;
      Ws[k4 + 2][m] = wv.z; Ws[k4 + 3][m] = wv.w;
    }
    __syncthreads();
#pragma unroll
    for (int kk = 0; kk < 32; ++kk) {
      const float4 a = *(const float4*)(&As[kk][ty * 4]);
      const float4 b = *(const float4*)(&Ws[kk][tx * 4]);
      acc[0][0] += a.x * b.x; acc[0][1] += a.x * b.y; acc[0][2] += a.x * b.z; acc[0][3] += a.x * b.w;
      acc[1][0] += a.y * b.x; acc[1][1] += a.y * b.y; acc[1][2] += a.y * b.z; acc[1][3] += a.y * b.w;
      acc[2][0] += a.z * b.x; acc[2][1] += a.z * b.y; acc[2][2] += a.z * b.z; acc[2][3] += a.z * b.w;
      acc[3][0] += a.w * b.x; acc[3][1] += a.w * b.y; acc[3][2] += a.w * b.z; acc[3][3] += a.w * b.w;
    }
    __syncthreads();
  }
  const float4 bv4 = *(const float4*)(beff + nBase + tx * 4);
#pragma unroll
  for (int im = 0; im < 4; ++im) {
    const int r = mBase + ty * 4 + im;
    float4 o;
    o.x = acc[im][0] + bv4.x;
    o.y = acc[im][1] + bv4.y;
    o.z = acc[im][2] + bv4.z;
    o.w = acc[im][3] + bv4.w;
    *(float4*)(out + (size_t)r * NFEAT + nBase + tx * 4) = o;
  }
}

extern "C" void kernel_launch(void* const* d_in, const int* in_sizes, int n_in,
                              void* d_out, int out_size, void* d_ws, size_t ws_size,
                              hipStream_t stream) {
  const float* q  = (const float*)d_in[0];
  const float* kv = (const float*)d_in[1];
  const float* Wq = (const float*)d_in[2];
  const float* bq = (const float*)d_in[3];
  const float* Wk = (const float*)d_in[4];
  // d_in[5] = bk: dropped (constant shift per softmax row -> no effect)
  const float* Wv = (const float*)d_in[6];
  const float* bv = (const float*)d_in[7];
  const float* Wo = (const float*)d_in[8];
  const float* bo = (const float*)d_in[9];
  float* out = (float*)d_out;

  float* ws = (float*)d_ws;
  float* km     = ws;                  // [8][128][1024]        = 1048576
  float* attn   = km + 1048576;        // [8][16][8][128]       = 131072
  float* Weff   = attn + 131072;       // [1024][1024]          = 1048576
  float* beff   = Weff + 1048576;      // [1024]                = 1024
  float* pooled = beff + 1024;         // [8][64][8][1024]      = 4194304
  // total ws: 6,423,552 floats = 25.7 MB

  mean_kernel<<<BDIM * LDIM, 256, 0, stream>>>(kv, km);
  attn_kernel<<<dim3(BDIM, HNUM), 128, 0, stream>>>(q, km, Wq, bq, Wk, attn);
  weff_kernel<<<NFEAT, 256, 0, stream>>>(Wo, Wv, bv, bo, Weff, beff);
  pool_kernel<<<dim3(BDIM, TDIM, 4), 64, 0, stream>>>(kv, attn, pooled);
  gemm_kernel<<<dim3(NFEAT / 64, 4096 / 64), 256, 0, stream>>>(pooled, Weff, beff, out);
}

// Round 2
// 153.674 us; speedup vs baseline: 1.6208x; 1.6208x over previous
//
#include <hip/hip_runtime.h>
#include <hip/hip_bf16.h>

#define BDIM 8
#define LDIM 128
#define TDIM 64
#define NFEAT 1024
#define HNUM 16
#define DH 64

#define GM 4096  // rows of pooled = B*T*B
#define GN 1024
#define GK 1024

typedef __attribute__((ext_vector_type(8))) short short8;
typedef __attribute__((ext_vector_type(4))) float f32x4;

// round-to-nearest-even f32 -> bf16 bits
__device__ __forceinline__ unsigned short f2bf(float x) {
  union { float f; unsigned u; } v; v.f = x;
  unsigned r = v.u + 0x7fffu + ((v.u >> 16) & 1u);
  return (unsigned short)(r >> 16);
}

__device__ __forceinline__ void gload_lds16(const void* g, void* l) {
  __builtin_amdgcn_global_load_lds((const __attribute__((address_space(1))) void*)g,
                                   (__attribute__((address_space(3))) void*)l, 16, 0, 0);
}

// ---------------------------------------------------------------------------
// Kernel 1: km[b,l,f] = mean over t of kv[b,l,t,f].  One block per (b,l) row.
// ---------------------------------------------------------------------------
__global__ __launch_bounds__(256) void mean_kernel(const float* __restrict__ kv,
                                                   float* __restrict__ km) {
  const int bl = blockIdx.x;  // b*L + l
  const float* src = kv + (size_t)bl * (TDIM * NFEAT) + threadIdx.x * 4;
  float4 acc = make_float4(0.f, 0.f, 0.f, 0.f);
#pragma unroll 4
  for (int t = 0; t < TDIM; ++t) {
    const float4 v = *(const float4*)(src + t * NFEAT);
    acc.x += v.x; acc.y += v.y; acc.z += v.z; acc.w += v.w;
  }
  const float s = 1.f / TDIM;
  const float4 o = make_float4(acc.x * s, acc.y * s, acc.z * s, acc.w * s);
  *(float4*)(km + (size_t)bl * NFEAT + threadIdx.x * 4) = o;
}

// ---------------------------------------------------------------------------
// Kernel 2: fused q-proj, k-proj (folded), QK^T, softmax -> attn[b1,h,b2,l]
// One block per (b1,h), 128 threads (one per l). bk dropped (softmax-invariant).
// ---------------------------------------------------------------------------
__global__ __launch_bounds__(128) void attn_kernel(const float* __restrict__ q,
                                                   const float* __restrict__ km,
                                                   const float* __restrict__ Wq,
                                                   const float* __restrict__ bq,
                                                   const float* __restrict__ Wk,
                                                   float* __restrict__ attn) {
  __shared__ float qp_s[BDIM * DH];
  __shared__ float qk_s[BDIM * DH];
  __shared__ float sw[BDIM * LDIM];
  __shared__ float mred[BDIM], ired[BDIM];
  const int b1 = blockIdx.x;
  const int h  = blockIdx.y;
  const int tid = threadIdx.x;

  {
    const int e0 = tid * 4;
    const int b2 = e0 >> 6;
    const int d0 = e0 & 63;
    float a0 = bq[d0], a1 = bq[d0 + 1], a2 = bq[d0 + 2], a3 = bq[d0 + 3];
    const float* qrow = q + b2 * NFEAT + h * DH;
#pragma unroll 4
    for (int i = 0; i < DH; ++i) {
      const float qv = qrow[i];
      a0 += qv * Wq[(d0 + 0) * DH + i];
      a1 += qv * Wq[(d0 + 1) * DH + i];
      a2 += qv * Wq[(d0 + 2) * DH + i];
      a3 += qv * Wq[(d0 + 3) * DH + i];
    }
    qp_s[e0 + 0] = a0; qp_s[e0 + 1] = a1; qp_s[e0 + 2] = a2; qp_s[e0 + 3] = a3;
  }
  __syncthreads();
  {
    const int e0 = tid * 4;
    const int b2 = e0 >> 6;
    const int i0 = e0 & 63;
    float a0 = 0, a1 = 0, a2 = 0, a3 = 0;
#pragma unroll 4
    for (int d = 0; d < DH; ++d) {
      const float qpv = qp_s[b2 * DH + d];
      const float4 wk4 = *(const float4*)(Wk + d * DH + i0);
      a0 += qpv * wk4.x; a1 += qpv * wk4.y; a2 += qpv * wk4.z; a3 += qpv * wk4.w;
    }
    qk_s[e0 + 0] = a0; qk_s[e0 + 1] = a1; qk_s[e0 + 2] = a2; qk_s[e0 + 3] = a3;
  }
  __syncthreads();
  const int l = tid;
  {
    const float* kmrow = km + (size_t)(b1 * LDIM + l) * NFEAT + h * DH;
    float s[8] = {0, 0, 0, 0, 0, 0, 0, 0};
#pragma unroll
    for (int i4 = 0; i4 < DH / 4; ++i4) {
      const float4 kmv = *(const float4*)(kmrow + i4 * 4);
#pragma unroll
      for (int b2 = 0; b2 < 8; ++b2) {
        const float4 qk4 = *(const float4*)(qk_s + b2 * DH + i4 * 4);
        s[b2] += kmv.x * qk4.x + kmv.y * qk4.y + kmv.z * qk4.z + kmv.w * qk4.w;
      }
    }
#pragma unroll
    for (int b2 = 0; b2 < 8; ++b2) sw[b2 * LDIM + l] = s[b2] * 0.125f;
  }
  __syncthreads();
  if (tid < 8) {
    const int b2 = tid;
    float m = -1e30f;
    for (int j = 0; j < LDIM; ++j) m = fmaxf(m, sw[b2 * LDIM + j]);
    float ssum = 0.f;
    for (int j = 0; j < LDIM; ++j) ssum += expf(sw[b2 * LDIM + j] - m);
    mred[b2] = m;
    ired[b2] = 1.f / ssum;
  }
  __syncthreads();
  float* abase = attn + ((size_t)(b1 * HNUM + h) * BDIM) * LDIM + l;
#pragma unroll
  for (int b2 = 0; b2 < 8; ++b2) {
    abase[b2 * LDIM] = expf(sw[b2 * LDIM + l] - mred[b2]) * ired[b2];
  }
}

// ---------------------------------------------------------------------------
// Kernel 3: Weff[f, h*64+i] = sum_d Wo[f,h*64+d]*Wv[d,i]   (bf16 output)
//           beff[f] = bo[f] + sum_g bv[g%64]*Wo[f,g]
// ---------------------------------------------------------------------------
__global__ __launch_bounds__(256) void weff_kernel(const float* __restrict__ Wo,
                                                   const float* __restrict__ Wv,
                                                   const float* __restrict__ bv,
                                                   const float* __restrict__ bo,
                                                   unsigned short* __restrict__ Weff,
                                                   float* __restrict__ beff) {
  __shared__ float worow[NFEAT];
  __shared__ float red[256];
  const int f = blockIdx.x;
  const int tid = threadIdx.x;
  *(float4*)(worow + tid * 4) = *(const float4*)(Wo + (size_t)f * NFEAT + tid * 4);
  __syncthreads();
  const int g0 = tid * 4;
  const int hbase = (g0 >> 6) << 6;
  const int i0 = g0 & 63;
  float a0 = 0, a1 = 0, a2 = 0, a3 = 0;
#pragma unroll 4
  for (int d = 0; d < DH; ++d) {
    const float wod = worow[hbase + d];
    const float4 wv4 = *(const float4*)(Wv + d * DH + i0);
    a0 += wod * wv4.x; a1 += wod * wv4.y; a2 += wod * wv4.z; a3 += wod * wv4.w;
  }
  ushort4 pk;
  pk.x = f2bf(a0); pk.y = f2bf(a1); pk.z = f2bf(a2); pk.w = f2bf(a3);
  *(ushort4*)(Weff + (size_t)f * NFEAT + g0) = pk;
  red[tid] = worow[g0 + 0] * bv[i0 + 0] + worow[g0 + 1] * bv[i0 + 1] +
             worow[g0 + 2] * bv[i0 + 2] + worow[g0 + 3] * bv[i0 + 3];
  __syncthreads();
  for (int sft = 128; sft > 0; sft >>= 1) {
    if (tid < sft) red[tid] += red[tid + sft];
    __syncthreads();
  }
  if (tid == 0) beff[f] = bo[f] + red[0];
}

// ---------------------------------------------------------------------------
// Kernel 4: pooled[b1][t][b2][f] = sum_l attn[b1, f/64, b2, l] * kv[b1,l,t,f]
// bf16 output. Streams kv exactly once (256 MB).
// ---------------------------------------------------------------------------
__global__ __launch_bounds__(64) void pool_kernel(const float* __restrict__ kv,
                                                  const float* __restrict__ attn,
                                                  unsigned short* __restrict__ pooled) {
  __shared__ float wlds[4 * BDIM * LDIM];
  const int b1 = blockIdx.x;
  const int t = blockIdx.y;
  const int ftile = blockIdx.z;
  const int tid = threadIdx.x;
  {
    const float* src = attn + ((size_t)(b1 * HNUM + ftile * 4)) * (BDIM * LDIM);
#pragma unroll
    for (int j = 0; j < 16; ++j) {
      const int idx = (j * 64 + tid) * 4;
      *(float4*)(wlds + idx) = *(const float4*)(src + idx);
    }
  }
  __syncthreads();
  const int f = ftile * 256 + tid * 4;
  const int hh = tid >> 4;
  const float* kvbase = kv + ((size_t)b1 * LDIM) * (TDIM * NFEAT) + t * NFEAT + f;
  float4 acc[8];
#pragma unroll
  for (int b2 = 0; b2 < 8; ++b2) acc[b2] = make_float4(0.f, 0.f, 0.f, 0.f);
  const float* wbase = wlds + hh * (BDIM * LDIM);
#pragma unroll 2
  for (int l = 0; l < LDIM; ++l) {
    const float4 v = *(const float4*)(kvbase + (size_t)l * (TDIM * NFEAT));
#pragma unroll
    for (int b2 = 0; b2 < 8; ++b2) {
      const float w = wbase[b2 * LDIM + l];
      acc[b2].x += w * v.x; acc[b2].y += w * v.y;
      acc[b2].z += w * v.z; acc[b2].w += w * v.w;
    }
  }
  unsigned short* obase = pooled + ((size_t)(b1 * TDIM + t) * BDIM) * NFEAT + f;
#pragma unroll
  for (int b2 = 0; b2 < 8; ++b2) {
    ushort4 pk;
    pk.x = f2bf(acc[b2].x); pk.y = f2bf(acc[b2].y);
    pk.z = f2bf(acc[b2].z); pk.w = f2bf(acc[b2].w);
    *(ushort4*)(obase + b2 * NFEAT) = pk;
  }
}

// ---------------------------------------------------------------------------
// Kernel 5: bf16 MFMA GEMM.  out[r][n] = sum_k A[r][k]*W[n][k] + beff[n]
// A=[4096][1024] bf16, W=[1024][1024] bf16, out fp32.
// 128x128 tile, BK=32, 4 waves (2x2), 16x16x32 MFMA, global_load_lds staging,
// both-sides XOR swizzle (chunk ^= (row>>1)&3) for conflict-free ds_read_b128.
// ---------------------------------------------------------------------------
__global__ __launch_bounds__(256) void mfma_gemm(const unsigned short* __restrict__ A,
                                                 const unsigned short* __restrict__ W,
                                                 const float* __restrict__ beff,
                                                 float* __restrict__ out) {
  __shared__ unsigned short As[128 * 32];
  __shared__ unsigned short Bs[128 * 32];
  const int tid = threadIdx.x;
  const int w = tid >> 6, l = tid & 63;
  const int mBase = blockIdx.y * 128, nBase = blockIdx.x * 128;
  const int wr = w >> 1, wc = w & 1;

  // staging lane constants: issue j covers LDS bytes [(w*2+j)*1024 + l*16, +16)
  int sr[2], sc[2];
#pragma unroll
  for (int j = 0; j < 2; ++j) {
    const int o = (w * 2 + j) * 1024 + l * 16;  // phys byte in tile
    const int r = o >> 6;                       // row (64 B per row of 32 bf16)
    const int c = (o >> 4) & 3;                 // phys 16B chunk
    sr[j] = r;
    sc[j] = (c ^ ((r >> 1) & 3)) * 8;           // logical k-element offset
  }
  // fragment read byte offsets (m=0 / n=0 base); (row>>1)&3 == (rl>>1)&3 here
  const int rl = l & 15, ks = l >> 4;
  const int fsel = (ks ^ ((rl >> 1) & 3)) * 16;
  const int aoff0 = (wr * 64 + rl) * 64 + fsel;
  const int boff0 = (wc * 64 + rl) * 64 + fsel;

  f32x4 acc[4][4] = {};
  for (int k0 = 0; k0 < GK; k0 += 32) {
#pragma unroll
    for (int j = 0; j < 2; ++j) {
      gload_lds16(A + (size_t)(mBase + sr[j]) * GK + k0 + sc[j],
                  (char*)As + (w * 2 + j) * 1024);
      gload_lds16(W + (size_t)(nBase + sr[j]) * GK + k0 + sc[j],
                  (char*)Bs + (w * 2 + j) * 1024);
    }
    __syncthreads();
    short8 a[4], b[4];
#pragma unroll
    for (int m = 0; m < 4; ++m)
      a[m] = *(const short8*)((const char*)As + aoff0 + m * 1024);
#pragma unroll
    for (int n = 0; n < 4; ++n)
      b[n] = *(const short8*)((const char*)Bs + boff0 + n * 1024);
#pragma unroll
    for (int m = 0; m < 4; ++m)
#pragma unroll
      for (int n = 0; n < 4; ++n)
        acc[m][n] = __builtin_amdgcn_mfma_f32_16x16x32_bf16(a[m], b[n], acc[m][n], 0, 0, 0);
    __syncthreads();
  }

  // epilogue: C/D layout col=lane&15, row=(lane>>4)*4+reg
#pragma unroll
  for (int n = 0; n < 4; ++n) {
    const int col = nBase + wc * 64 + n * 16 + rl;
    const float bv = beff[col];
#pragma unroll
    for (int m = 0; m < 4; ++m) {
      const int row0 = mBase + wr * 64 + m * 16 + ks * 4;
#pragma unroll
      for (int j2 = 0; j2 < 4; ++j2)
        out[(size_t)(row0 + j2) * GN + col] = acc[m][n][j2] + bv;
    }
  }
}

extern "C" void kernel_launch(void* const* d_in, const int* in_sizes, int n_in,
                              void* d_out, int out_size, void* d_ws, size_t ws_size,
                              hipStream_t stream) {
  const float* q  = (const float*)d_in[0];
  const float* kv = (const float*)d_in[1];
  const float* Wq = (const float*)d_in[2];
  const float* bq = (const float*)d_in[3];
  const float* Wk = (const float*)d_in[4];
  // d_in[5] = bk: dropped (constant shift per softmax row -> no effect)
  const float* Wv = (const float*)d_in[6];
  const float* bv = (const float*)d_in[7];
  const float* Wo = (const float*)d_in[8];
  const float* bo = (const float*)d_in[9];
  float* out = (float*)d_out;

  char* ws = (char*)d_ws;
  float*          km     = (float*)ws;                              // 4 MB
  float*          attn   = (float*)(ws + (4u << 20));               // 512 KB
  float*          beff   = (float*)(ws + (4u << 20) + (512u << 10));  // 4 KB
  unsigned short* Weff   = (unsigned short*)(ws + (4u << 20) + (516u << 10));          // 2 MB
  unsigned short* pooled = (unsigned short*)(ws + (4u << 20) + (516u << 10) + (2u << 20));  // 8 MB

  mean_kernel<<<BDIM * LDIM, 256, 0, stream>>>(kv, km);
  attn_kernel<<<dim3(BDIM, HNUM), 128, 0, stream>>>(q, km, Wq, bq, Wk, attn);
  weff_kernel<<<NFEAT, 256, 0, stream>>>(Wo, Wv, bv, bo, Weff, beff);
  pool_kernel<<<dim3(BDIM, TDIM, 4), 64, 0, stream>>>(kv, attn, pooled);
  mfma_gemm<<<dim3(GN / 128, GM / 128), 256, 0, stream>>>(pooled, Weff, beff, out);
}

// Round 3
// 147.944 us; speedup vs baseline: 1.6836x; 1.0387x over previous
//
#include <hip/hip_runtime.h>
#include <hip/hip_bf16.h>

#define BDIM 8
#define LDIM 128
#define TDIM 64
#define NFEAT 1024
#define HNUM 16
#define DH 64

#define GM 4096  // rows of pooled = B*T*B
#define GN 1024
#define GK 1024

typedef __attribute__((ext_vector_type(8))) short short8;
typedef __attribute__((ext_vector_type(4))) float f32x4;

// round-to-nearest-even f32 -> bf16 bits
__device__ __forceinline__ unsigned short f2bf(float x) {
  union { float f; unsigned u; } v; v.f = x;
  unsigned r = v.u + 0x7fffu + ((v.u >> 16) & 1u);
  return (unsigned short)(r >> 16);
}

__device__ __forceinline__ void gload_lds16(const void* g, void* l) {
  __builtin_amdgcn_global_load_lds((const __attribute__((address_space(1))) void*)g,
                                   (__attribute__((address_space(3))) void*)l, 16, 0, 0);
}

// ---------------------------------------------------------------------------
// Kernel 1: km[b,l,f] = mean over t of kv[b,l,t,f].  One block per (b,l) row.
// 8-deep load batch per iteration to keep >=8 x 16B in flight per wave.
// ---------------------------------------------------------------------------
__global__ __launch_bounds__(256) void mean_kernel(const float* __restrict__ kv,
                                                   float* __restrict__ km) {
  const int bl = blockIdx.x;  // b*L + l
  const float* src = kv + (size_t)bl * (TDIM * NFEAT) + threadIdx.x * 4;
  float4 acc = make_float4(0.f, 0.f, 0.f, 0.f);
  for (int t0 = 0; t0 < TDIM; t0 += 8) {
    float4 v[8];
#pragma unroll
    for (int j = 0; j < 8; ++j) v[j] = *(const float4*)(src + (t0 + j) * NFEAT);
#pragma unroll
    for (int j = 0; j < 8; ++j) {
      acc.x += v[j].x; acc.y += v[j].y; acc.z += v[j].z; acc.w += v[j].w;
    }
  }
  const float s = 1.f / TDIM;
  const float4 o = make_float4(acc.x * s, acc.y * s, acc.z * s, acc.w * s);
  *(float4*)(km + (size_t)bl * NFEAT + threadIdx.x * 4) = o;
}

// ---------------------------------------------------------------------------
// Kernel 2: fused q-proj, k-proj (folded), QK^T, softmax -> attn[b1,h,b2,l]
// One block per (b1,h), 128 threads (one per l). bk dropped (softmax-invariant).
// ---------------------------------------------------------------------------
__global__ __launch_bounds__(128) void attn_kernel(const float* __restrict__ q,
                                                   const float* __restrict__ km,
                                                   const float* __restrict__ Wq,
                                                   const float* __restrict__ bq,
                                                   const float* __restrict__ Wk,
                                                   float* __restrict__ attn) {
  __shared__ float qp_s[BDIM * DH];
  __shared__ float qk_s[BDIM * DH];
  __shared__ float sw[BDIM * LDIM];
  __shared__ float mred[BDIM], ired[BDIM];
  const int b1 = blockIdx.x;
  const int h  = blockIdx.y;
  const int tid = threadIdx.x;

  {
    const int e0 = tid * 4;
    const int b2 = e0 >> 6;
    const int d0 = e0 & 63;
    float a0 = bq[d0], a1 = bq[d0 + 1], a2 = bq[d0 + 2], a3 = bq[d0 + 3];
    const float* qrow = q + b2 * NFEAT + h * DH;
#pragma unroll 4
    for (int i = 0; i < DH; ++i) {
      const float qv = qrow[i];
      a0 += qv * Wq[(d0 + 0) * DH + i];
      a1 += qv * Wq[(d0 + 1) * DH + i];
      a2 += qv * Wq[(d0 + 2) * DH + i];
      a3 += qv * Wq[(d0 + 3) * DH + i];
    }
    qp_s[e0 + 0] = a0; qp_s[e0 + 1] = a1; qp_s[e0 + 2] = a2; qp_s[e0 + 3] = a3;
  }
  __syncthreads();
  {
    const int e0 = tid * 4;
    const int b2 = e0 >> 6;
    const int i0 = e0 & 63;
    float a0 = 0, a1 = 0, a2 = 0, a3 = 0;
#pragma unroll 4
    for (int d = 0; d < DH; ++d) {
      const float qpv = qp_s[b2 * DH + d];
      const float4 wk4 = *(const float4*)(Wk + d * DH + i0);
      a0 += qpv * wk4.x; a1 += qpv * wk4.y; a2 += qpv * wk4.z; a3 += qpv * wk4.w;
    }
    qk_s[e0 + 0] = a0; qk_s[e0 + 1] = a1; qk_s[e0 + 2] = a2; qk_s[e0 + 3] = a3;
  }
  __syncthreads();
  const int l = tid;
  {
    const float* kmrow = km + (size_t)(b1 * LDIM + l) * NFEAT + h * DH;
    float s[8] = {0, 0, 0, 0, 0, 0, 0, 0};
#pragma unroll
    for (int i4 = 0; i4 < DH / 4; ++i4) {
      const float4 kmv = *(const float4*)(kmrow + i4 * 4);
#pragma unroll
      for (int b2 = 0; b2 < 8; ++b2) {
        const float4 qk4 = *(const float4*)(qk_s + b2 * DH + i4 * 4);
        s[b2] += kmv.x * qk4.x + kmv.y * qk4.y + kmv.z * qk4.z + kmv.w * qk4.w;
      }
    }
#pragma unroll
    for (int b2 = 0; b2 < 8; ++b2) sw[b2 * LDIM + l] = s[b2] * 0.125f;
  }
  __syncthreads();
  if (tid < 8) {
    const int b2 = tid;
    float m = -1e30f;
    for (int j = 0; j < LDIM; ++j) m = fmaxf(m, sw[b2 * LDIM + j]);
    float ssum = 0.f;
    for (int j = 0; j < LDIM; ++j) ssum += expf(sw[b2 * LDIM + j] - m);
    mred[b2] = m;
    ired[b2] = 1.f / ssum;
  }
  __syncthreads();
  float* abase = attn + ((size_t)(b1 * HNUM + h) * BDIM) * LDIM + l;
#pragma unroll
  for (int b2 = 0; b2 < 8; ++b2) {
    abase[b2 * LDIM] = expf(sw[b2 * LDIM + l] - mred[b2]) * ired[b2];
  }
}

// ---------------------------------------------------------------------------
// Kernel 3: Weff[f, h*64+i] = sum_d Wo[f,h*64+d]*Wv[d,i]   (bf16 output)
//           beff[f] = bo[f] + sum_g bv[g%64]*Wo[f,g]
// ---------------------------------------------------------------------------
__global__ __launch_bounds__(256) void weff_kernel(const float* __restrict__ Wo,
                                                   const float* __restrict__ Wv,
                                                   const float* __restrict__ bv,
                                                   const float* __restrict__ bo,
                                                   unsigned short* __restrict__ Weff,
                                                   float* __restrict__ beff) {
  __shared__ float worow[NFEAT];
  __shared__ float red[256];
  const int f = blockIdx.x;
  const int tid = threadIdx.x;
  *(float4*)(worow + tid * 4) = *(const float4*)(Wo + (size_t)f * NFEAT + tid * 4);
  __syncthreads();
  const int g0 = tid * 4;
  const int hbase = (g0 >> 6) << 6;
  const int i0 = g0 & 63;
  float a0 = 0, a1 = 0, a2 = 0, a3 = 0;
#pragma unroll 4
  for (int d = 0; d < DH; ++d) {
    const float wod = worow[hbase + d];
    const float4 wv4 = *(const float4*)(Wv + d * DH + i0);
    a0 += wod * wv4.x; a1 += wod * wv4.y; a2 += wod * wv4.z; a3 += wod * wv4.w;
  }
  ushort4 pk;
  pk.x = f2bf(a0); pk.y = f2bf(a1); pk.z = f2bf(a2); pk.w = f2bf(a3);
  *(ushort4*)(Weff + (size_t)f * NFEAT + g0) = pk;
  red[tid] = worow[g0 + 0] * bv[i0 + 0] + worow[g0 + 1] * bv[i0 + 1] +
             worow[g0 + 2] * bv[i0 + 2] + worow[g0 + 3] * bv[i0 + 3];
  __syncthreads();
  for (int sft = 128; sft > 0; sft >>= 1) {
    if (tid < sft) red[tid] += red[tid + sft];
    __syncthreads();
  }
  if (tid == 0) beff[f] = bo[f] + red[0];
}

// ---------------------------------------------------------------------------
// Kernel 4: pooled[b1][t][b2][f] = sum_l attn[b1, f/64, b2, l] * kv[b1,l,t,f]
// bf16 output. Streams kv exactly once. 8-deep load batches; attn in LDS with
// per-head stride 1032 floats (1032%32==8 -> hh-groups hit banks 0/8/16/24,
// conflict-free broadcast reads).
// ---------------------------------------------------------------------------
#define HSTRIDE 1032
__global__ __launch_bounds__(64) void pool_kernel(const float* __restrict__ kv,
                                                  const float* __restrict__ attn,
                                                  unsigned short* __restrict__ pooled) {
  __shared__ float wlds[4 * HSTRIDE];
  const int b1 = blockIdx.x;
  const int t = blockIdx.y;
  const int ftile = blockIdx.z;
  const int tid = threadIdx.x;
  {
#pragma unroll
    for (int hg = 0; hg < 4; ++hg) {
      const float* src = attn + ((size_t)(b1 * HNUM + ftile * 4 + hg)) * (BDIM * LDIM);
#pragma unroll
      for (int j = 0; j < 4; ++j) {
        const int idx = (j * 64 + tid) * 4;
        *(float4*)(wlds + hg * HSTRIDE + idx) = *(const float4*)(src + idx);
      }
    }
  }
  __syncthreads();
  const int f = ftile * 256 + tid * 4;
  const int hh = tid >> 4;
  const float* kvbase = kv + ((size_t)b1 * LDIM) * (TDIM * NFEAT) + t * NFEAT + f;
  float4 acc[8];
#pragma unroll
  for (int b2 = 0; b2 < 8; ++b2) acc[b2] = make_float4(0.f, 0.f, 0.f, 0.f);
  const float* wbase = wlds + hh * HSTRIDE;
  for (int l0 = 0; l0 < LDIM; l0 += 8) {
    float4 v[8];
#pragma unroll
    for (int j = 0; j < 8; ++j)
      v[j] = *(const float4*)(kvbase + (size_t)(l0 + j) * (TDIM * NFEAT));
#pragma unroll
    for (int j = 0; j < 8; ++j) {
#pragma unroll
      for (int b2 = 0; b2 < 8; ++b2) {
        const float w = wbase[b2 * LDIM + l0 + j];
        acc[b2].x += w * v[j].x; acc[b2].y += w * v[j].y;
        acc[b2].z += w * v[j].z; acc[b2].w += w * v[j].w;
      }
    }
  }
  unsigned short* obase = pooled + ((size_t)(b1 * TDIM + t) * BDIM) * NFEAT + f;
#pragma unroll
  for (int b2 = 0; b2 < 8; ++b2) {
    ushort4 pk;
    pk.x = f2bf(acc[b2].x); pk.y = f2bf(acc[b2].y);
    pk.z = f2bf(acc[b2].z); pk.w = f2bf(acc[b2].w);
    *(ushort4*)(obase + b2 * NFEAT) = pk;
  }
}

// ---------------------------------------------------------------------------
// Kernel 5: bf16 MFMA GEMM.  out[r][n] = sum_k A[r][k]*W[n][k] + beff[n]
// 128x64 tile (512 blocks = 2 blocks/CU for cross-block overlap), BK=32,
// 4 waves (2x2 -> 64x32 per wave), LDS double-buffer, 2-phase schedule:
// stage next K-tile (global_load_lds w=16) BEFORE ds_read+MFMA of current,
// single barrier per K-step. Both-sides XOR swizzle (chunk ^= (row>>1)&3).
// ---------------------------------------------------------------------------
__global__ __launch_bounds__(256) void mfma_gemm(const unsigned short* __restrict__ A,
                                                 const unsigned short* __restrict__ W,
                                                 const float* __restrict__ beff,
                                                 float* __restrict__ out) {
  __shared__ unsigned short As[2][128 * 32];
  __shared__ unsigned short Bs[2][64 * 32];
  const int tid = threadIdx.x;
  const int w = tid >> 6, l = tid & 63;
  const int mBase = blockIdx.y * 128, nBase = blockIdx.x * 64;
  const int wr = w >> 1, wc = w & 1;

  // staging constants: A tile = 512 16B chunks (2/thread), B tile = 256 (1/thread)
  int arow[2], acol[2];
#pragma unroll
  for (int j = 0; j < 2; ++j) {
    const int cid = j * 256 + tid;
    const int r = cid >> 2, c = cid & 3;
    arow[j] = r;
    acol[j] = (c ^ ((r >> 1) & 3)) * 8;  // k-element offset of this chunk
  }
  const int brow = tid >> 2;
  const int bcol = ((tid & 3) ^ ((brow >> 1) & 3)) * 8;

  const int rl = l & 15, ks = l >> 4;
  const int fsel = (ks ^ ((rl >> 1) & 3)) * 16;  // swizzled byte offset of k-slot

  f32x4 acc[4][2] = {};

  // prologue: stage k-tile 0 into buffer 0
#pragma unroll
  for (int j = 0; j < 2; ++j)
    gload_lds16(A + (size_t)(mBase + arow[j]) * GK + acol[j],
                (char*)As[0] + (j * 256 + tid) * 16);
  gload_lds16(W + (size_t)(nBase + brow) * GK + bcol, (char*)Bs[0] + tid * 16);
  __syncthreads();

  int cur = 0;
  for (int t = 0; t < GK / 32; ++t) {
    if (t + 1 < GK / 32) {
      const int k0 = (t + 1) * 32;
#pragma unroll
      for (int j = 0; j < 2; ++j)
        gload_lds16(A + (size_t)(mBase + arow[j]) * GK + k0 + acol[j],
                    (char*)As[cur ^ 1] + (j * 256 + tid) * 16);
      gload_lds16(W + (size_t)(nBase + brow) * GK + k0 + bcol,
                  (char*)Bs[cur ^ 1] + tid * 16);
    }
    short8 a[4], b[2];
#pragma unroll
    for (int m = 0; m < 4; ++m)
      a[m] = *(const short8*)((const char*)As[cur] + (wr * 64 + m * 16 + rl) * 64 + fsel);
#pragma unroll
    for (int n = 0; n < 2; ++n)
      b[n] = *(const short8*)((const char*)Bs[cur] + (wc * 32 + n * 16 + rl) * 64 + fsel);
#pragma unroll
    for (int m = 0; m < 4; ++m)
#pragma unroll
      for (int n = 0; n < 2; ++n)
        acc[m][n] = __builtin_amdgcn_mfma_f32_16x16x32_bf16(a[m], b[n], acc[m][n], 0, 0, 0);
    __syncthreads();  // drains vmcnt(0): next buffer staged; cur reads done
    cur ^= 1;
  }

  // epilogue: C/D layout col=lane&15, row=(lane>>4)*4+reg
#pragma unroll
  for (int n = 0; n < 2; ++n) {
    const int col = nBase + wc * 32 + n * 16 + rl;
    const float bv = beff[col];
#pragma unroll
    for (int m = 0; m < 4; ++m) {
      const int row0 = mBase + wr * 64 + m * 16 + ks * 4;
#pragma unroll
      for (int j2 = 0; j2 < 4; ++j2)
        out[(size_t)(row0 + j2) * GN + col] = acc[m][n][j2] + bv;
    }
  }
}

extern "C" void kernel_launch(void* const* d_in, const int* in_sizes, int n_in,
                              void* d_out, int out_size, void* d_ws, size_t ws_size,
                              hipStream_t stream) {
  const float* q  = (const float*)d_in[0];
  const float* kv = (const float*)d_in[1];
  const float* Wq = (const float*)d_in[2];
  const float* bq = (const float*)d_in[3];
  const float* Wk = (const float*)d_in[4];
  // d_in[5] = bk: dropped (constant shift per softmax row -> no effect)
  const float* Wv = (const float*)d_in[6];
  const float* bv = (const float*)d_in[7];
  const float* Wo = (const float*)d_in[8];
  const float* bo = (const float*)d_in[9];
  float* out = (float*)d_out;

  char* ws = (char*)d_ws;
  float*          km     = (float*)ws;                                // 4 MB
  float*          attn   = (float*)(ws + (4u << 20));                 // 512 KB
  float*          beff   = (float*)(ws + (4u << 20) + (512u << 10));  // 4 KB
  unsigned short* Weff   = (unsigned short*)(ws + (4u << 20) + (516u << 10));               // 2 MB
  unsigned short* pooled = (unsigned short*)(ws + (4u << 20) + (516u << 10) + (2u << 20));  // 8 MB

  // weff first (independent) so pool's kv read follows mean's stream closely (L3 reuse)
  weff_kernel<<<NFEAT, 256, 0, stream>>>(Wo, Wv, bv, bo, Weff, beff);
  mean_kernel<<<BDIM * LDIM, 256, 0, stream>>>(kv, km);
  attn_kernel<<<dim3(BDIM, HNUM), 128, 0, stream>>>(q, km, Wq, bq, Wk, attn);
  pool_kernel<<<dim3(BDIM, TDIM, 4), 64, 0, stream>>>(kv, attn, pooled);
  mfma_gemm<<<dim3(GN / 64, GM / 128), 256, 0, stream>>>(pooled, Weff, beff, out);
}